// Round 10
// baseline (1795.682 us; speedup 1.0000x reference)
//
#include <hip/hip_runtime.h>
#include <cstdint>
#include <cstddef>

// PlainRNN fused: h_{t+1} = tanh(h_t @ W_eff + b_eff), traj[t] = h_t @ W_h2o + b_h2o
// W_eff = W_h2h + W_h2o @ W_i2h  (recurrence composition removes x from the loop)
//
// Persistent kernel: 16 groups (16 batch rows each) x 16 blocks (72 of 1152 cols).
// Groups formed DYNAMICALLY per-XCD (HW_REG_XCC_ID + per-XCD slot counter):
// all 16 members share one XCD L2 BY CONSTRUCTION.
//
// R15 = R7 skeleton with 8 WAVES/BLOCK (2 per SIMD): shrink the BODY, not the sync.
//   Ledger: R5 1600 | R6 3667 (poll flood) | R7 1452 (BEST; 4 waves, 1/SIMD) |
//   R8/R11/R12 (L2-local flags impossible: agent scope required, ~1.0-1.3us
//   floor) | R9 2251 (chain multiplex; measured body ~1.5us, sync ~1.3us) |
//   R10 3542 (per-wave flags + 4x pollers melt) | R13 1582 (coarse self-release:
//   reduce barrier re-couples to the global straggler) | R14 FAIL (dataflow
//   chunks: 64B chunks share 128B lines -> early load caches the other half
//   stale (R8 mechanism on the data path) + per-arrival agent-RT detect cost).
//   R15: the body ran at 1 wave/SIMD in every round — all latencies exposed.
//   8 waves x K=128: per-wave MFMA 40->20, af 8->4, bw 40->20 v8h (80 VGPR,
//   fits 2 waves/SIMD's 256-VGPR budget at ~150 total); co-resident waves
//   hide each other's af/LDS/store latencies. Reduce widens to 7 ranks
//   (35KB LDS, tile c owner = wave c, waves 5-7 contribute only).
//   EVERYTHING else frozen at R7: 16 member flags on one 128B line, tid0
//   agent-relaxed store after the drain barrier, wave0-only throttled agent
//   poll (s_sleep backoff, tries-bounded), 3 barriers, pass1/pass2 split,
//   bias hoist, 96KB dyn LDS -> 1 block/CU -> 32 blocks/XCD placement,
//   4-slot hbuf rotation (32KB/step x 4 slots streams the 32KB L1 ->
//   always-fresh XCD-L2 hits on plain loads).

#define BATCH  256
#define INPUT  128
#define HIDDEN 1024
#define OUTPUT 128
#define TSTEPS 512
#define NCAT   1152
#define NTILE  72
#define GROUPS 16
#define MEMB   16
#define NSLOT  4
#define WAVES  8
#define KSL    128      // K-slice per wave
#define KCH    4        // kk chunks (32 cols) per wave

// workspace layout (bytes)
#define WS_WFRAG 0u
#define WS_BEFF  2621440u
#define WS_HBUF  2629632u                 // 4 slots x 256x1024 f16 = 4x524288
#define WS_BAR   4726784u
// bar[] u32: [g*32 + mem]   per-member step flags (one 128B line per group)
//            [512 + xcc*32] per-XCD slot counters (one-time)
#define BAR_U32S 768

typedef _Float16 f16;
typedef _Float16 v8h __attribute__((ext_vector_type(8)));
typedef float    v4f __attribute__((ext_vector_type(4)));

__device__ __forceinline__ float fast_tanh(float x){
  float e = __expf(2.0f * x);
  return (e - 1.0f) / (e + 1.0f);
}

// ---- bias composition
__global__ void k_bias(const float* __restrict__ bi2h, const float* __restrict__ bh2h,
                       const float* __restrict__ bh2o, const float* __restrict__ Wi2h,
                       float* __restrict__ beff){
  int n = blockIdx.x*256 + threadIdx.x;
  if (n >= 1168) return;
  float v = 0.f;
  if (n < HIDDEN){
    v = bi2h[n] + bh2h[n];
    for (int j=0;j<INPUT;j++) v += bh2o[j]*Wi2h[j*HIDDEN + n];
  } else if (n < NCAT){
    v = bh2o[n - HIDDEN];
  }
  beff[n] = v;
}

// ---- h_1 = tanh(x0 @ W_i2h + b_i2h + b_h2h) -> slot 0
__global__ void k_h1(const float* __restrict__ x0, const float* __restrict__ Wi2h,
                     const float* __restrict__ bi2h, const float* __restrict__ bh2h,
                     f16* __restrict__ hbuf){
  int idx = blockIdx.x*256 + threadIdx.x;
  int m = idx >> 10, n = idx & 1023;
  float acc = bi2h[n] + bh2h[n];
  const float* xr = x0 + m*INPUT;
  for (int j=0;j<INPUT;j++) acc += xr[j]*Wi2h[j*HIDDEN + n];
  hbuf[idx] = (f16)fast_tanh(acc);
}

// ---- traj[0] = x_0
__global__ void k_copy0(const float* __restrict__ x0, float* __restrict__ out){
  int i = blockIdx.x*256 + threadIdx.x;
  out[i] = x0[i];
}

// ---- W fragment packing: [mem 16][wave 8][kk 4][c 5][lane 64][8 halves]
__global__ void k_wfrag(const float* __restrict__ Wh2h, const float* __restrict__ Wh2o,
                        const float* __restrict__ Wi2h, f16* __restrict__ Wfrag){
  int gid = blockIdx.x*256 + threadIdx.x;
  int lane = gid & 63;
  int fi = gid >> 6;                       // 0..2559
  int c = fi % 5, kk = (fi/5) & 3, wv = (fi/20) & 7, mem = fi/160;
  int k0 = wv*KSL + kk*32 + (lane>>4)*8;
  int n  = mem*NTILE + c*16 + (lane & 15);
  f16 vals[8];
  if (n >= NCAT){
    #pragma unroll
    for (int j=0;j<8;j++) vals[j] = (f16)0.f;
  } else if (n >= HIDDEN){
    #pragma unroll
    for (int j=0;j<8;j++) vals[j] = (f16)Wh2o[(k0+j)*OUTPUT + (n-HIDDEN)];
  } else {
    float acc[8];
    #pragma unroll
    for (int j=0;j<8;j++) acc[j] = Wh2h[(k0+j)*HIDDEN + n];
    for (int q=0;q<INPUT;q++){
      float wi = Wi2h[q*HIDDEN + n];
      #pragma unroll
      for (int j=0;j<8;j++) acc[j] += Wh2o[(k0+j)*OUTPUT + q]*wi;
    }
    #pragma unroll
    for (int j=0;j<8;j++) vals[j] = (f16)acc[j];
  }
  v8h pack;
  #pragma unroll
  for (int j=0;j<8;j++) pack[j] = vals[j];
  *(v8h*)(Wfrag + (size_t)gid*8) = pack;
}

// ---- persistent recurrence kernel: 256 blocks x 512 threads (8 waves, 2/SIMD),
// 1 block/CU via 96KB dyn LDS.
__global__ void __launch_bounds__(512, 2)
k_rnn(const f16* __restrict__ Wfrag, const float* __restrict__ beff,
      f16* __restrict__ hbuf, unsigned int* __restrict__ bar,
      float* __restrict__ out){
  extern __shared__ char lds_raw[];
  float*    red    = (float*)lds_raw;              // [c5][rank7][lane64][4] f32 = 35840 B
  unsigned* s_slot = (unsigned*)(lds_raw + 36864);

  const int tid  = threadIdx.x;
  const int lane = tid & 63;
  const int wv   = tid >> 6;               // 0..7

  // Dynamic same-XCD group formation. 1 block/CU + grid==CU count => 32 blocks/XCD.
  // Group = xcc*2 + slot/16, member = slot%16: group shares one XCD L2 BY CONSTRUCTION.
  if (tid == 0){
    unsigned xcc;
    asm volatile("s_getreg_b32 %0, hwreg(HW_REG_XCC_ID)" : "=s"(xcc));
    xcc &= 7;
    unsigned slot = atomicAdd(&bar[512 + xcc*32], 1u);  // one-time, device-scope
    *s_slot = xcc*32 + (slot & 31u);
  }
  __syncthreads();
  const unsigned sid = *s_slot;
  const int g   = sid >> 4;
  const int mem = sid & 15;
  if (g >= GROUPS) return;
  const int m0   = g * 16;
  const int n0   = mem * NTILE;
  const int quad = lane >> 4;
  const int l15  = lane & 15;

  // B fragments resident in registers for the whole 511-step loop.
  // Per wave: K-slice 128 -> bw[4][5] = 20 v8h = 80 VGPR.
  v8h bw[KCH][5];
  {
    const f16* wp = Wfrag + ((size_t)((mem*WAVES + wv)*20)*64 + lane)*8;
    #pragma unroll
    for (int kk=0;kk<KCH;kk++)
      #pragma unroll
      for (int c=0;c<5;c++)
        bw[kk][c] = *(const v8h*)(wp + (size_t)((kk*5+c)*64)*8);
  }

  // Tile ownership: tile c (c=0..4) owned by wave c; waves 5-7 contribute only.
  // Bias hoisted to a register (beff load always missed L1 — A-stream evicts it).
  float bown = 0.f;
  if (wv < 5){
    int colT = wv*16 + l15;
    int col  = n0 + colT;
    if (colT < NTILE && col < NCAT) bown = beff[col];
  }

  const int kbase = wv*KSL;
  unsigned int* flg = bar + g*32;   // 16 per-member flags, one 128B line per group

  for (int t=1; t<TSTEPS; ++t){
    // ---- wait: all 16 member flags >= t-1. Wave 0 ONLY (poller count is the
    // traffic knob — R6/R10): lanes poll flg[lane&15] (one transaction, one
    // line, agent-relaxed), s_sleep(1) backoff. R7-proven.
    // Bounded: broken sync degrades to a visible timeout, never a hang.
    if (wv == 0){
      const unsigned target = (unsigned)(t-1);
      unsigned tries = 0;
      for (;;){
        unsigned f = __hip_atomic_load(flg + (lane & 15), __ATOMIC_RELAXED,
                                       __HIP_MEMORY_SCOPE_AGENT);
        if (__all((int)(f >= target))) break;
        if (++tries > 2048u) break;
        __builtin_amdgcn_s_sleep(1);
      }
    }
    __syncthreads();   // release: waves 1-7 park here while wave 0 polls

    const f16* hin  = hbuf + (size_t)((t-1)&(NSLOT-1))*(BATCH*HIDDEN);
    f16*       hout = hbuf + (size_t)(t&(NSLOT-1))*(BATCH*HIDDEN);

    // A fragments: plain vector loads. 4-slot rotation guarantees the L1 line
    // for this address was evicted (32KB/step x 4-slot reuse distance = 128KB
    // streamed through the 32KB L1) => miss L1, hit the shared XCD L2 (fresh).
    // lane holds A[m=l15][k = kbase + kk*32 + quad*8 + j].
    v8h af[KCH];
    {
      const v8h* abase = (const v8h*)(hin + (size_t)(m0 + l15)*HIDDEN + kbase + quad*8);
      #pragma unroll
      for (int kk=0;kk<KCH;kk++)
        af[kk] = abase[kk*4];            // stride 32 halves = 4 v8h
    }

    v4f acc[5];
    #pragma unroll
    for (int c=0;c<5;c++){ v4f z = {0.f,0.f,0.f,0.f}; acc[c] = z; }

    #pragma unroll
    for (int kk=0;kk<KCH;kk++){
      #pragma unroll
      for (int c=0;c<5;c++)
        acc[c] = __builtin_amdgcn_mfma_f32_16x16x32_f16(af[kk], bw[kk][c], acc[c], 0,0,0);
    }

    // cross-wave K reduction via LDS. tile c owner = wave c; 7 non-owner ranks.
    #pragma unroll
    for (int c=0;c<5;c++){
      if (wv != c){
        int rank = (wv > c) ? wv-1 : wv;
        *(v4f*)(red + ((size_t)(c*7 + rank)*64 + lane)*4) = acc[c];
      }
    }
    __syncthreads();   // reduce visibility

    // pass 1: hidden columns (consumed by the group next step) -> plain stores
    // into the XCD L2. Owner wave c stores tile c.
    if (wv < 5){
      const int c = wv;
      int colT = c*16 + l15;
      int col  = n0 + colT;
      if (col < HIDDEN && colT < NTILE){
        v4f s = acc[c];
        #pragma unroll
        for (int r=0;r<7;r++) s += *(const v4f*)(red + ((size_t)(c*7 + r)*64 + lane)*4);
        #pragma unroll
        for (int r=0;r<4;r++){
          float v = fast_tanh(s[r] + bown);
          hout[(size_t)(m0 + quad*4 + r)*HIDDEN + col] = (f16)v;  // C/D: col=lane&15,row=quad*4+r
        }
      }
    }
    __syncthreads();   // drain: each wave waits vmcnt(0) => all h stores acked in L2

    // arrival: ONE agent-relaxed store per member (R7-proven form & traffic).
    // h-then-flag order guaranteed by the drain barrier's vmcnt(0).
    if (tid == 0)
      __hip_atomic_store(flg + mem, (unsigned)t, __ATOMIC_RELAXED,
                         __HIP_MEMORY_SCOPE_AGENT);

    // pass 2: y columns (consumed by nobody) — after the flag, off the critical
    // path; overlaps group-mates' polling.
    if (wv < 5){
      const int c = wv;
      int colT = c*16 + l15;
      int col  = n0 + colT;
      if (col >= HIDDEN && colT < NTILE){
        v4f s = acc[c];
        #pragma unroll
        for (int r=0;r<7;r++) s += *(const v4f*)(red + ((size_t)(c*7 + r)*64 + lane)*4);
        float* op = out + (size_t)t*(BATCH*OUTPUT) + (col - HIDDEN);
        #pragma unroll
        for (int r=0;r<4;r++)
          op[(size_t)(m0 + quad*4 + r)*OUTPUT] = s[r] + bown;
      }
    }
  }
}

extern "C" void kernel_launch(void* const* d_in, const int* in_sizes, int n_in,
                              void* d_out, int out_size, void* d_ws, size_t ws_size,
                              hipStream_t stream){
  const float* x0   = (const float*)d_in[0];
  const float* Wi2h = (const float*)d_in[1];
  const float* bi2h = (const float*)d_in[2];
  const float* Wh2h = (const float*)d_in[3];
  const float* bh2h = (const float*)d_in[4];
  const float* Wh2o = (const float*)d_in[5];
  const float* bh2o = (const float*)d_in[6];
  float* out = (float*)d_out;
  char* ws = (char*)d_ws;

  f16*          Wfrag = (f16*)(ws + WS_WFRAG);
  float*        beff  = (float*)(ws + WS_BEFF);
  f16*          hbuf  = (f16*)(ws + WS_HBUF);
  unsigned int* bar   = (unsigned int*)(ws + WS_BAR);

  hipMemsetAsync(bar, 0, BAR_U32S*sizeof(unsigned int), stream);
  k_bias <<<5,    256, 0, stream>>>(bi2h, bh2h, bh2o, Wi2h, beff);
  k_h1   <<<1024, 256, 0, stream>>>(x0, Wi2h, bi2h, bh2h, hbuf);
  k_copy0<<<128,  256, 0, stream>>>(x0, out);
  k_wfrag<<<640,  256, 0, stream>>>(Wh2h, Wh2o, Wi2h, Wfrag);

  // 96KB dynamic LDS forces 1 block/CU -> all 256 blocks co-resident, 32 per
  // XCD (the placement invariant). 512 threads = 8 waves = 2 waves/SIMD.
  hipFuncSetAttribute((const void*)k_rnn, hipFuncAttributeMaxDynamicSharedMemorySize, 98304);
  k_rnn<<<256, 512, 98304, stream>>>(Wfrag, beff, hbuf, bar, out);
}